// Round 4
// baseline (53.166 us; speedup 1.0000x reference)
//
#include <hip/hip_runtime.h>
#include <math.h>

// Shapes (hard-coded per reference setup_inputs):
//   b=16, t=128, c=t-1=127, kv_dim=k=64, h=4, q_dim=256
#define Bdim 16
#define Tdim 128
#define Cdim 127
#define Hdim 4
#define QD   256
#define HK   256   // h*k

// ---------------------------------------------------------------------------
// K1: M[i, h*64+m] = sum_j Wq[i,h*64+j] * Wk[m,h*64+j]
// grid (128 i-pairs, 2 head-pairs); Wk head-pair slice staged in LDS with +1
// pad (banks (m+kk)%32 -> 2-way, free). All global reads/writes coalesced.
__global__ __launch_bounds__(256) void precompute_M(
        const float* __restrict__ Wq, const float* __restrict__ Wk,
        float* __restrict__ M) {
    __shared__ float wk_s[64][129];   // Wk[m][H*128+kk], padded
    __shared__ float wq_s[2][128];    // two Wq row-slices
    int I = blockIdx.x;               // i-pair
    int H = blockIdx.y;               // head-pair (heads 2H, 2H+1)
    int tid = threadIdx.x;

    #pragma unroll
    for (int it = 0; it < 8; ++it) {
        int flat = tid + it * 256;            // 2048 float4 total
        int m = flat >> 5, kq = flat & 31;    // 32 float4 per row-slice
        float4 v = *(const float4*)(Wk + m * HK + H * 128 + kq * 4);
        wk_s[m][kq*4+0] = v.x; wk_s[m][kq*4+1] = v.y;
        wk_s[m][kq*4+2] = v.z; wk_s[m][kq*4+3] = v.w;
    }
    if (tid < 64) {
        int r = tid >> 5, kq = tid & 31;
        float4 v = *(const float4*)(Wq + (size_t)(I*2+r) * HK + H * 128 + kq * 4);
        wq_s[r][kq*4+0] = v.x; wq_s[r][kq*4+1] = v.y;
        wq_s[r][kq*4+2] = v.z; wq_s[r][kq*4+3] = v.w;
    }
    __syncthreads();

    int r = tid >> 7, hh = (tid >> 6) & 1, m = tid & 63;  // r,hh wave-uniform
    float acc = 0.f;
    #pragma unroll 8
    for (int j = 0; j < 64; ++j)
        acc = fmaf(wq_s[r][hh*64+j], wk_s[m][hh*64+j], acc);  // bcast + 2-way
    M[(size_t)(I*2+r) * HK + H * 128 + hh * 64 + m] = acc;
}

// ---------------------------------------------------------------------------
// K2: qk = q_x @ M, K-split into NS partial buffers (summed in attn_main).
// grid (128 row-blocks, NS); 16 rows x 256 cols per block; thread = column.
template <int NS>
__global__ __launch_bounds__(256) void qk_gemm(
        const float* __restrict__ q_x,
        const float* __restrict__ M,
        float* __restrict__ part) {
    const int KLEN = 256 / NS;
    __shared__ __align__(16) float q_s[16][256 / NS];
    int RB = blockIdx.x;
    int S  = blockIdx.y;
    int tid = threadIdx.x;

    for (int f = tid; f < 16 * KLEN / 4; f += 256) {
        int r = f / (KLEN / 4), kq = f % (KLEN / 4);
        *(float4*)&q_s[r][kq*4] =
            *(const float4*)(q_x + (size_t)(RB*16 + r) * QD + S * KLEN + kq * 4);
    }
    __syncthreads();

    float acc[16];
    #pragma unroll
    for (int r = 0; r < 16; ++r) acc[r] = 0.f;

    for (int kk = 0; kk < KLEN / 4; ++kk) {
        int k = S * KLEN + kk * 4;
        float m0 = M[(size_t)(k+0) * HK + tid];   // coalesced, L2-hot
        float m1 = M[(size_t)(k+1) * HK + tid];
        float m2 = M[(size_t)(k+2) * HK + tid];
        float m3 = M[(size_t)(k+3) * HK + tid];
        #pragma unroll
        for (int r = 0; r < 16; ++r) {
            float4 qv = *(const float4*)&q_s[r][kk*4];   // b128 broadcast
            acc[r] = fmaf(qv.x, m0, fmaf(qv.y, m1, fmaf(qv.z, m2, fmaf(qv.w, m3, acc[r]))));
        }
    }
    float* dst = part + (size_t)S * (Bdim*Tdim*HK) + (size_t)RB * 16 * HK + tid;
    #pragma unroll
    for (int r = 0; r < 16; ++r) dst[r * HK] = acc[r];
}

// ---------------------------------------------------------------------------
// K3: per (b,t): scores -> softmax -> wx (unnormalized) -> V-proj (scaled).
// 512 threads / 8 waves per block; 4 blocks/CU x 8 waves = 32 waves/CU capacity.
// X row-major in LDS, float4 chunks, XOR slot swizzle phys = log ^ (c&7).
// Staged via global_load_lds (linear LDS dest, pre-swizzled global source).
__global__ __launch_bounds__(512, 8) void attn_main(
        const float* __restrict__ kv_x,
        const float* __restrict__ qk_p, int nsplit,
        const float* __restrict__ Wv,
        float* __restrict__ out) {
    __shared__ __align__(16) float4 sX4[128 * 16];        // 32 KB; row 127 zeroed
    __shared__ __align__(16) float qk_s[HK];
    __shared__ __align__(16) float w_lds[Hdim * 128];     // unnormalized e
    __shared__ __align__(16) float wx_part[Hdim][2][64];  // per c-half partials
    __shared__ float red_max[Hdim][2];
    __shared__ float red_sum[Hdim][2];

    int bt  = blockIdx.x;
    int tid = threadIdx.x;

    // ---- stage: issue async loads FIRST (latency hides under qk sum) ----
    const float4* Xg = (const float4*)(kv_x + (size_t)bt * (Cdim * 64));
    #pragma unroll
    for (int it = 0; it < 4; ++it) {
        int l = tid + it * 512;                 // linear LDS chunk index
        if (l < Cdim * 16) {
            int c = l >> 4, p = l & 15;
            __builtin_amdgcn_global_load_lds(
                (const __attribute__((address_space(1))) void*)(Xg + (c << 4) + (p ^ (c & 7))),
                (__attribute__((address_space(3))) void*)(sX4 + l), 16, 0, 0);
        }
    }
    if (tid >= 256 && tid < 320)
        ((float*)sX4)[Cdim * 64 + (tid - 256)] = 0.f;     // zero pad row 127
    if (tid < 256) {
        float q = 0.f;
        for (int s = 0; s < nsplit; ++s)
            q += qk_p[(size_t)s * (Bdim*Tdim*HK) + (size_t)bt * HK + tid];
        qk_s[tid] = q;
    }
    __syncthreads();                                      // barrier 1

    int h    = tid >> 7;          // head, wave-uniform
    int c    = tid & 127;         // this thread's context row
    int half = (tid >> 6) & 1;    // which wave of the head pair
    int lane = tid & 63;

    // ---- scores: one row-dot per thread ----
    float s = 0.f;
    {
        const float4* qrow = (const float4*)(qk_s + h * 64);
        const float4* xp = sX4 + c * 16;
        int sw = c & 7;
        #pragma unroll
        for (int ss = 0; ss < 16; ++ss) {
            float4 qv = qrow[ss];                // b128 broadcast
            float4 a = xp[ss ^ sw];              // 8 lanes/bank-group, distinct rows
            s = fmaf(qv.x, a.x, fmaf(qv.y, a.y, fmaf(qv.z, a.z, fmaf(qv.w, a.w, s))));
        }
    }
    s = (c < Cdim) ? s * 0.125f : -INFINITY;     // 1/sqrt(64); row 127 is pad

    // ---- softmax over 128 threads (2 waves), normalization deferred ----
    float mx = s;
    #pragma unroll
    for (int mask = 1; mask <= 32; mask <<= 1)
        mx = fmaxf(mx, __shfl_xor(mx, mask, 64));
    if (lane == 0) red_max[h][half] = mx;
    __syncthreads();                                      // barrier 2
    float gm = fmaxf(red_max[h][0], red_max[h][1]);
    float e = __expf(s - gm);                    // c==127: exp(-inf)=0
    w_lds[h * 128 + c] = e;
    float sm = e;
    #pragma unroll
    for (int mask = 1; mask <= 32; mask <<= 1)
        sm += __shfl_xor(sm, mask, 64);
    if (lane == 0) red_sum[h][half] = sm;
    __syncthreads();                                      // barrier 3

    // ---- wx[h][j] = sum_c e[c]*X[c][j]; thread = (cgrp 0..31, jgrp 0..3) ----
    {
        int idx = tid & 127;
        int cgrp = idx >> 2, jgrp = idx & 3;
        float4 a0 = {0,0,0,0}, a1 = {0,0,0,0}, a2 = {0,0,0,0}, a3 = {0,0,0,0};
        #pragma unroll
        for (int i = 0; i < 4; ++i) {
            int ii = (i + cgrp) & 3;             // rotated c-order (bank spread)
            int cc = cgrp * 4 + ii;              // c==127 -> e=0, row zeroed
            float wv = w_lds[h * 128 + cc];
            const float4* row = sX4 + cc * 16;
            int sw = cc & 7;
            float4 x0 = row[(jgrp*4 + 0) ^ sw];
            float4 x1 = row[(jgrp*4 + 1) ^ sw];
            float4 x2 = row[(jgrp*4 + 2) ^ sw];
            float4 x3 = row[(jgrp*4 + 3) ^ sw];
            a0.x = fmaf(wv, x0.x, a0.x); a0.y = fmaf(wv, x0.y, a0.y);
            a0.z = fmaf(wv, x0.z, a0.z); a0.w = fmaf(wv, x0.w, a0.w);
            a1.x = fmaf(wv, x1.x, a1.x); a1.y = fmaf(wv, x1.y, a1.y);
            a1.z = fmaf(wv, x1.z, a1.z); a1.w = fmaf(wv, x1.w, a1.w);
            a2.x = fmaf(wv, x2.x, a2.x); a2.y = fmaf(wv, x2.y, a2.y);
            a2.z = fmaf(wv, x2.z, a2.z); a2.w = fmaf(wv, x2.w, a2.w);
            a3.x = fmaf(wv, x3.x, a3.x); a3.y = fmaf(wv, x3.y, a3.y);
            a3.z = fmaf(wv, x3.z, a3.z); a3.w = fmaf(wv, x3.w, a3.w);
        }
        // reduce across the 16 cgrp-lanes of this wave (lane bits 2..5)
        #pragma unroll
        for (int mask = 4; mask <= 32; mask <<= 1) {
            a0.x += __shfl_xor(a0.x, mask, 64); a0.y += __shfl_xor(a0.y, mask, 64);
            a0.z += __shfl_xor(a0.z, mask, 64); a0.w += __shfl_xor(a0.w, mask, 64);
            a1.x += __shfl_xor(a1.x, mask, 64); a1.y += __shfl_xor(a1.y, mask, 64);
            a1.z += __shfl_xor(a1.z, mask, 64); a1.w += __shfl_xor(a1.w, mask, 64);
            a2.x += __shfl_xor(a2.x, mask, 64); a2.y += __shfl_xor(a2.y, mask, 64);
            a2.z += __shfl_xor(a2.z, mask, 64); a2.w += __shfl_xor(a2.w, mask, 64);
            a3.x += __shfl_xor(a3.x, mask, 64); a3.y += __shfl_xor(a3.y, mask, 64);
            a3.z += __shfl_xor(a3.z, mask, 64); a3.w += __shfl_xor(a3.w, mask, 64);
        }
        if ((lane >> 2) == 0) {                  // lanes 0..3 (= jgrp)
            float4* wdst = (float4*)(&wx_part[h][half][jgrp * 16]);
            wdst[0] = a0; wdst[1] = a1; wdst[2] = a2; wdst[3] = a3;
        }
    }
    __syncthreads();                                      // barrier 4

    // ---- out[h,k] = inv * sum_j wx[h,j] * Wv[j, h*64+k]; tid<256 ----
    if (tid < 256) {
        int hh = tid >> 6, k = tid & 63;
        float inv = 1.f / (red_sum[hh][0] + red_sum[hh][1]);
        const float* wA = wx_part[hh][0];
        const float* wB = wx_part[hh][1];
        const float* wvcol = Wv + hh * 64 + k;
        float acc = 0.f;
        #pragma unroll 4
        for (int j = 0; j < 64; ++j)
            acc = fmaf(wA[j] + wB[j], wvcol[(size_t)j * HK], acc);  // coalesced
        out[(size_t)bt * HK + tid] = acc * inv;
    }
}

extern "C" void kernel_launch(void* const* d_in, const int* in_sizes, int n_in,
                              void* d_out, int out_size, void* d_ws, size_t ws_size,
                              hipStream_t stream) {
    const float* q_x  = (const float*)d_in[0];   // [16,128,256]
    const float* kv_x = (const float*)d_in[1];   // [16,128,127,64]
    const float* Wq   = (const float*)d_in[2];   // [256,256]
    const float* Wk   = (const float*)d_in[3];   // [64,256]
    const float* Wv   = (const float*)d_in[4];   // [64,256]
    float* out = (float*)d_out;                  // [16,128,256] f32

    float* M     = (float*)d_ws;                 // 256*256 floats
    float* parts = M + 256 * 256;                // NS * 2048*256 floats

    size_t need4 = (size_t)(256*256 + 4 * Bdim*Tdim*HK) * sizeof(float);
    int nsplit = (ws_size >= need4) ? 4 : 1;

    precompute_M<<<dim3(128, 2), 256, 0, stream>>>(Wq, Wk, M);
    if (nsplit == 4)
        qk_gemm<4><<<dim3(128, 4), 256, 0, stream>>>(q_x, M, parts);
    else
        qk_gemm<1><<<dim3(128, 1), 256, 0, stream>>>(q_x, M, parts);
    attn_main<<<Bdim * Tdim, 512, 0, stream>>>(kv_x, parts, nsplit, Wv, out);
}